// Round 1
// 1126.901 us; speedup vs baseline: 1.0432x; 1.0432x over previous
//
#include <hip/hip_runtime.h>
#include <math.h>

// Problem constants (fixed by setup_inputs)
#define BB 4
#define HH 128
#define DD 512
#define WW 512
#define GG 72
#define PP 65536
#define CHUNK 256
#define NCHUNK (PP / CHUNK)          // 256
#define HDW (HH * DD * WW)           // 33,554,432
#define NBRICK (HDW / 8)             // 4,194,304 bricks of 2x2x2 voxels

typedef _Float16 half4 __attribute__((ext_vector_type(4)));
typedef _Float16 half8 __attribute__((ext_vector_type(8)));

// ---------------------------------------------------------------------------
// Transpose + quantize into 64B bricks:
//   ct [B,H,D,W] fp32  ->  tv bricks: brick(bz,by,bx) holds 2x2x2 voxels x 4
//   batches fp16, inner layout [oz][oy][ox][b] -> 32 halves = 64 B = 1 line.
// One thread per brick; reads are 8B (float2) coalesced across bx.
// ---------------------------------------------------------------------------
__global__ __launch_bounds__(256) void k_transpose(
    const float* __restrict__ ct, _Float16* __restrict__ tv)
{
    const int n  = blockIdx.x * 256 + threadIdx.x;   // brick index
    const int bx = n & 255;                          // WW/2 = 256
    const int by = (n >> 8) & 255;                   // DD/2 = 256
    const int bz = n >> 16;                          // HH/2 = 64
    const size_t base = ((size_t)(2 * bz) * DD + 2 * by) * WW + 2 * bx;

    half8 o0, o1, o2, o3;   // o[k] covers inner voxels 2k,2k+1 (4 halves each)
#pragma unroll
    for (int b = 0; b < BB; ++b) {
        const float* v = ct + (size_t)b * HDW + base;
        const float2 f00 = *(const float2*)(v);                       // oz0 oy0
        const float2 f01 = *(const float2*)(v + WW);                  // oz0 oy1
        const float2 f10 = *(const float2*)(v + (size_t)DD * WW);     // oz1 oy0
        const float2 f11 = *(const float2*)(v + (size_t)DD * WW + WW);// oz1 oy1
        o0[b] = (_Float16)f00.x; o0[4 + b] = (_Float16)f00.y;
        o1[b] = (_Float16)f01.x; o1[4 + b] = (_Float16)f01.y;
        o2[b] = (_Float16)f10.x; o2[4 + b] = (_Float16)f10.y;
        o3[b] = (_Float16)f11.x; o3[4 + b] = (_Float16)f11.y;
    }
    _Float16* dst = tv + (size_t)n * 32;
    *(half8*)(dst)      = o0;
    *(half8*)(dst + 8)  = o1;
    *(half8*)(dst + 16) = o2;
    *(half8*)(dst + 24) = o3;
}

// ---------------------------------------------------------------------------
// Shared epilogue: block reduction of 4 chunk sums + dist. Accumulates with
// atomics so the two slab passes can both contribute (buffers memset first).
// ---------------------------------------------------------------------------
__device__ __forceinline__ void density_reduce(
    const float dens[BB], float dist, int g, int chunk, int t, int do_dist,
    float* __restrict__ chunk_sums, float* __restrict__ step_accum)
{
    __shared__ float wsum[4][5];
    const int lane = t & 63;
    const int wid  = t >> 6;
    float r0 = dens[0], r1 = dens[1], r2 = dens[2], r3 = dens[3], rd = dist;
#pragma unroll
    for (int off = 32; off > 0; off >>= 1) {
        r0 += __shfl_xor(r0, off);
        r1 += __shfl_xor(r1, off);
        r2 += __shfl_xor(r2, off);
        r3 += __shfl_xor(r3, off);
        rd += __shfl_xor(rd, off);
    }
    if (lane == 0) {
        wsum[wid][0] = r0; wsum[wid][1] = r1; wsum[wid][2] = r2;
        wsum[wid][3] = r3; wsum[wid][4] = rd;
    }
    __syncthreads();
    if (t == 0) {
        float s0 = 0, s1 = 0, s2 = 0, s3 = 0, sd = 0;
#pragma unroll
        for (int w = 0; w < 4; ++w) {
            s0 += wsum[w][0]; s1 += wsum[w][1]; s2 += wsum[w][2];
            s3 += wsum[w][3]; sd += wsum[w][4];
        }
        atomicAdd(&chunk_sums[((size_t)(0 * GG + g)) * NCHUNK + chunk], s0);
        atomicAdd(&chunk_sums[((size_t)(1 * GG + g)) * NCHUNK + chunk], s1);
        atomicAdd(&chunk_sums[((size_t)(2 * GG + g)) * NCHUNK + chunk], s2);
        atomicAdd(&chunk_sums[((size_t)(3 * GG + g)) * NCHUNK + chunk], s3);
        if (do_dist) atomicAdd(&step_accum[g], sd);
    }
}

// half-element offset of corner voxel (zc,yc,xc) in the brick volume
__device__ __forceinline__ int brick_off(int zc, int yc, int xc)
{
    const int brick = ((zc >> 1) << 16) | ((yc >> 1) << 8) | (xc >> 1);
    const int inner = ((zc & 1) << 2) | ((yc & 1) << 1) | (xc & 1);
    return (brick << 5) | (inner << 2);
}

// Coord staging + per-thread setup, shared by both density kernels.
struct PointSetup {
    int i000, i001, i010, i011, i100, i101, i110, i111;
    float xd, yd, zd, dist;
    int slab;   // z0 >> 6 : which half-volume this point gathers from
};

template <bool BRICK>
__device__ __forceinline__ PointSetup point_setup(
    const float* __restrict__ coords, int g, int chunk, int t, int p)
{
    __shared__ float cbuf[(CHUNK + 1) * 3];
    const int nload = (chunk == NCHUNK - 1) ? CHUNK * 3 : (CHUNK + 1) * 3;
    const float* src = coords + ((size_t)g * PP + (size_t)chunk * CHUNK) * 3;
    for (int i = t; i < nload; i += CHUNK) cbuf[i] = src[i];
    __syncthreads();

    const float cx = cbuf[3 * t + 0];
    const float cy = cbuf[3 * t + 1];
    const float cz = cbuf[3 * t + 2];

    PointSetup s;
    s.dist = 0.0f;
    if (p < PP - 1) {
        const int nt = 3 * (t + 1);
        const float dx = cbuf[nt + 0] - cx;
        const float dy = cbuf[nt + 1] - cy;
        const float dz = cbuf[nt + 2] - cz;
        s.dist = sqrtf(dx * dx + dy * dy + dz * dz);
    }

    const float x = fminf(fmaxf(cx, 0.0f), (float)(WW - 1));
    const float y = fminf(fmaxf(cy, 0.0f), (float)(DD - 1));
    const float z = fminf(fmaxf(cz, 0.0f), (float)(HH - 1));
    const int x0 = (int)floorf(x);
    const int y0 = (int)floorf(y);
    const int z0 = (int)floorf(z);
    const int x1 = min(x0 + 1, WW - 1);
    const int y1 = min(y0 + 1, DD - 1);
    const int z1 = min(z0 + 1, HH - 1);
    s.xd = x - (float)x0;
    s.yd = y - (float)y0;
    s.zd = z - (float)z0;
    s.slab = z0 >> 6;

    if (BRICK) {
        s.i000 = brick_off(z0, y0, x0); s.i001 = brick_off(z0, y0, x1);
        s.i010 = brick_off(z0, y1, x0); s.i011 = brick_off(z0, y1, x1);
        s.i100 = brick_off(z1, y0, x0); s.i101 = brick_off(z1, y0, x1);
        s.i110 = brick_off(z1, y1, x0); s.i111 = brick_off(z1, y1, x1);
    } else {
        const int b00 = (z0 * DD + y0) * WW;
        const int b01 = (z0 * DD + y1) * WW;
        const int b10 = (z1 * DD + y0) * WW;
        const int b11 = (z1 * DD + y1) * WW;
        s.i000 = b00 + x0; s.i001 = b00 + x1;
        s.i010 = b01 + x0; s.i011 = b01 + x1;
        s.i100 = b10 + x0; s.i101 = b10 + x1;
        s.i110 = b11 + x0; s.i111 = b11 + x1;
    }
    return s;
}

// ---------------------------------------------------------------------------
// Fast density kernel: gathers from fp16 brick volume. Runs twice, once per
// z-slab (slab = z0>>6), so each pass's 128/132 MiB working set is
// L3-resident. grid = (NCHUNK, GG), block = 256, 1 point per thread.
// ---------------------------------------------------------------------------
__global__ __launch_bounds__(256) void k_density_h(
    const _Float16* __restrict__ tv,    // brick volume fp16
    const float* __restrict__ coords,   // [G, P, 3]
    float* __restrict__ density,        // [B*G, P]  (aliases d_out)
    float* __restrict__ chunk_sums,     // [B*G, NCHUNK]
    float* __restrict__ step_accum,     // [G]
    int slab, int do_dist)
{
    const int chunk = blockIdx.x;
    const int g     = blockIdx.y;
    const int t     = threadIdx.x;
    const int p     = chunk * CHUNK + t;

    const PointSetup s = point_setup<true>(coords, g, chunk, t, p);
    const bool member = (s.slab == slab);

    float dens[BB];
#pragma unroll
    for (int b = 0; b < BB; ++b) dens[b] = 0.0f;

    if (member) {
        const half4 a000 = *(const half4*)(tv + (size_t)s.i000);
        const half4 a001 = *(const half4*)(tv + (size_t)s.i001);
        const half4 a010 = *(const half4*)(tv + (size_t)s.i010);
        const half4 a011 = *(const half4*)(tv + (size_t)s.i011);
        const half4 a100 = *(const half4*)(tv + (size_t)s.i100);
        const half4 a101 = *(const half4*)(tv + (size_t)s.i101);
        const half4 a110 = *(const half4*)(tv + (size_t)s.i110);
        const half4 a111 = *(const half4*)(tv + (size_t)s.i111);
#pragma unroll
        for (int b = 0; b < BB; ++b) {
            const float c000 = (float)a000[b], c001 = (float)a001[b];
            const float c010 = (float)a010[b], c011 = (float)a011[b];
            const float c100 = (float)a100[b], c101 = (float)a101[b];
            const float c110 = (float)a110[b], c111 = (float)a111[b];
            const float c00 = c000 * (1.0f - s.xd) + c001 * s.xd;
            const float c01 = c010 * (1.0f - s.xd) + c011 * s.xd;
            const float c10 = c100 * (1.0f - s.xd) + c101 * s.xd;
            const float c11 = c110 * (1.0f - s.xd) + c111 * s.xd;
            const float c0  = c00 * (1.0f - s.yd) + c01 * s.yd;
            const float c1  = c10 * (1.0f - s.yd) + c11 * s.yd;
            dens[b] = c0 * (1.0f - s.zd) + c1 * s.zd;
            density[((size_t)(b * GG + g)) * PP + p] = dens[b];
        }
    }

    density_reduce(dens, s.dist, g, chunk, t, do_dist, chunk_sums, step_accum);
}

// ---------------------------------------------------------------------------
// Fallback density kernel (fp32 direct gather) — used if ws too small.
// ---------------------------------------------------------------------------
__global__ __launch_bounds__(256) void k_density(
    const float* __restrict__ ct,
    const float* __restrict__ coords,
    float* __restrict__ density,
    float* __restrict__ chunk_sums,
    float* __restrict__ step_accum)
{
    const int chunk = blockIdx.x;
    const int g     = blockIdx.y;
    const int t     = threadIdx.x;
    const int p     = chunk * CHUNK + t;

    const PointSetup s = point_setup<false>(coords, g, chunk, t, p);

    float dens[BB];
#pragma unroll
    for (int b = 0; b < BB; ++b) {
        const float* v = ct + (size_t)b * HDW;
        const float c000 = v[s.i000], c001 = v[s.i001];
        const float c010 = v[s.i010], c011 = v[s.i011];
        const float c100 = v[s.i100], c101 = v[s.i101];
        const float c110 = v[s.i110], c111 = v[s.i111];
        const float c00 = c000 * (1.0f - s.xd) + c001 * s.xd;
        const float c01 = c010 * (1.0f - s.xd) + c011 * s.xd;
        const float c10 = c100 * (1.0f - s.xd) + c101 * s.xd;
        const float c11 = c110 * (1.0f - s.xd) + c111 * s.xd;
        const float c0  = c00 * (1.0f - s.yd) + c01 * s.yd;
        const float c1  = c10 * (1.0f - s.yd) + c11 * s.yd;
        dens[b] = c0 * (1.0f - s.zd) + c1 * s.zd;
        density[((size_t)(b * GG + g)) * PP + p] = dens[b];
    }

    density_reduce(dens, s.dist, g, chunk, t, 1, chunk_sums, step_accum);
}

// ---------------------------------------------------------------------------
// Kernel 2: in-place exclusive scan of chunk sums per row. grid = B*G, blk=256
// ---------------------------------------------------------------------------
__global__ __launch_bounds__(256) void k_scan_chunks(float* __restrict__ cs)
{
    const int row = blockIdx.x;      // b*G + g
    const int t   = threadIdx.x;
    const int lane = t & 63;
    const int wid  = t >> 6;

    float v = cs[(size_t)row * NCHUNK + t];
    const float own = v;
#pragma unroll
    for (int d = 1; d < 64; d <<= 1) {
        const float n = __shfl_up(v, d);
        if (lane >= d) v += n;
    }
    __shared__ float ws[4];
    if (lane == 63) ws[wid] = v;
    __syncthreads();
    float prefix = 0.0f;
    for (int w = 0; w < wid; ++w) prefix += ws[w];
    cs[(size_t)row * NCHUNK + t] = prefix + v - own;   // exclusive
}

// ---------------------------------------------------------------------------
// Kernel 3: final scan + scale, in place over d_out. grid = (NCHUNK, GG)
// ---------------------------------------------------------------------------
__global__ __launch_bounds__(256) void k_output(
    float* __restrict__ out,
    const float* __restrict__ cs,
    const float* __restrict__ step_accum)
{
    const int chunk = blockIdx.x;
    const int g     = blockIdx.y;
    const int t     = threadIdx.x;
    const int p     = chunk * CHUNK + t;
    const int lane  = t & 63;
    const int wid   = t >> 6;

    const float step = step_accum[g] * (2.0f / (float)(PP - 1));

    float d[BB], v[BB];
#pragma unroll
    for (int b = 0; b < BB; ++b) {
        d[b] = out[((size_t)(b * GG + g)) * PP + p];
        v[b] = d[b];
    }

#pragma unroll
    for (int dd = 1; dd < 64; dd <<= 1) {
#pragma unroll
        for (int b = 0; b < BB; ++b) {
            const float n = __shfl_up(v[b], dd);
            if (lane >= dd) v[b] += n;
        }
    }
    __shared__ float ws[4][BB];
    if (lane == 63) {
#pragma unroll
        for (int b = 0; b < BB; ++b) ws[wid][b] = v[b];
    }
    __syncthreads();

#pragma unroll
    for (int b = 0; b < BB; ++b) {
        float prefix = 0.0f;
        for (int w = 0; w < wid; ++w) prefix += ws[w][b];
        const float excl = cs[((size_t)(b * GG + g)) * NCHUNK + chunk];
        const float incl = excl + prefix + v[b];
        out[((size_t)(b * GG + g)) * PP + p] = step * (incl + 0.5f * d[b]);
    }
}

// ---------------------------------------------------------------------------
extern "C" void kernel_launch(void* const* d_in, const int* in_sizes, int n_in,
                              void* d_out, int out_size, void* d_ws, size_t ws_size,
                              hipStream_t stream)
{
    const float* ct     = (const float*)d_in[0];
    const float* coords = (const float*)d_in[1];
    float* out = (float*)d_out;

    const size_t volBytes = (size_t)HDW * BB * sizeof(_Float16);        // 256 MiB
    const size_t csCount  = (size_t)BB * GG * NCHUNK;
    const size_t needed   = volBytes + (csCount + GG) * sizeof(float);

    if (ws_size >= needed) {
        _Float16* tv       = (_Float16*)d_ws;
        float* chunk_sums  = (float*)((char*)d_ws + volBytes);
        float* step_accum  = chunk_sums + csCount;

        // zero chunk_sums + step_accum together (they are adjacent)
        hipMemsetAsync(chunk_sums, 0, (csCount + GG) * sizeof(float), stream);
        k_transpose<<<NBRICK / 256, 256, 0, stream>>>(ct, tv);
        // slab 1 first: transpose wrote the volume in ascending z, so the
        // high-z half is the part most likely still resident in L3.
        k_density_h<<<dim3(NCHUNK, GG), 256, 0, stream>>>(tv, coords, out, chunk_sums, step_accum, 1, 1);
        k_density_h<<<dim3(NCHUNK, GG), 256, 0, stream>>>(tv, coords, out, chunk_sums, step_accum, 0, 0);
        k_scan_chunks<<<BB * GG, 256, 0, stream>>>(chunk_sums);
        k_output<<<dim3(NCHUNK, GG), 256, 0, stream>>>(out, chunk_sums, step_accum);
    } else {
        float* chunk_sums  = (float*)d_ws;
        float* step_accum  = chunk_sums + csCount;

        hipMemsetAsync(chunk_sums, 0, (csCount + GG) * sizeof(float), stream);
        k_density<<<dim3(NCHUNK, GG), 256, 0, stream>>>(ct, coords, out, chunk_sums, step_accum);
        k_scan_chunks<<<BB * GG, 256, 0, stream>>>(chunk_sums);
        k_output<<<dim3(NCHUNK, GG), 256, 0, stream>>>(out, chunk_sums, step_accum);
    }
}

// Round 3
// 1046.915 us; speedup vs baseline: 1.1229x; 1.0764x over previous
//
#include <hip/hip_runtime.h>
#include <math.h>

// Problem constants (fixed by setup_inputs)
#define BB 4
#define HH 128
#define DD 512
#define WW 512
#define GG 72
#define PP 65536
#define CHUNK 256
#define NCHUNK (PP / CHUNK)          // 256
#define HDW (HH * DD * WW)           // 33,554,432
#define NBRICK (HDW / 8)             // 4,194,304 bricks of 2x2x2 voxels

typedef _Float16 half4 __attribute__((ext_vector_type(4)));
typedef _Float16 half8 __attribute__((ext_vector_type(8)));
typedef float f4 __attribute__((ext_vector_type(4)));   // NT-load-compatible

// ---------------------------------------------------------------------------
// Transpose + quantize into 64B bricks:
//   ct [B,H,D,W] fp32  ->  tv bricks: brick(bz,by,bx) holds 2x2x2 voxels x 4
//   batches fp16, inner layout [oz][oy][ox][b] -> 32 halves = 64 B = 1 line.
// One thread per brick-PAIR (adjacent in x): f4 NT reads, 128 B write.
// NT on ct reads so the 512 MiB stream doesn't evict the tv slab from L3.
// ---------------------------------------------------------------------------
__global__ __launch_bounds__(256) void k_transpose(
    const float* __restrict__ ct, _Float16* __restrict__ tv)
{
    const int n2  = blockIdx.x * 256 + threadIdx.x;  // brick-pair index
    const int bxp = n2 & 127;                        // 128 pairs per x-row
    const int by  = (n2 >> 7) & 255;                 // DD/2
    const int bz  = n2 >> 15;                        // HH/2
    const size_t base = ((size_t)(2 * bz) * DD + 2 * by) * WW + 4 * bxp;

    half8 o00, o01, o02, o03;   // brick 0: inner pairs (oz,oy) = 00,01,10,11
    half8 o10, o11, o12, o13;   // brick 1
#pragma unroll
    for (int b = 0; b < BB; ++b) {
        const float* v = ct + (size_t)b * HDW + base;
        const f4 f00 = __builtin_nontemporal_load((const f4*)(v));
        const f4 f01 = __builtin_nontemporal_load((const f4*)(v + WW));
        const f4 f10 = __builtin_nontemporal_load((const f4*)(v + (size_t)DD * WW));
        const f4 f11 = __builtin_nontemporal_load((const f4*)(v + (size_t)DD * WW + WW));
        o00[b] = (_Float16)f00[0]; o00[4 + b] = (_Float16)f00[1];
        o01[b] = (_Float16)f01[0]; o01[4 + b] = (_Float16)f01[1];
        o02[b] = (_Float16)f10[0]; o02[4 + b] = (_Float16)f10[1];
        o03[b] = (_Float16)f11[0]; o03[4 + b] = (_Float16)f11[1];
        o10[b] = (_Float16)f00[2]; o10[4 + b] = (_Float16)f00[3];
        o11[b] = (_Float16)f01[2]; o11[4 + b] = (_Float16)f01[3];
        o12[b] = (_Float16)f10[2]; o12[4 + b] = (_Float16)f10[3];
        o13[b] = (_Float16)f11[2]; o13[4 + b] = (_Float16)f11[3];
    }
    _Float16* dst = tv + (size_t)n2 * 64;   // two consecutive 64 B bricks
    *(half8*)(dst)      = o00;
    *(half8*)(dst + 8)  = o01;
    *(half8*)(dst + 16) = o02;
    *(half8*)(dst + 24) = o03;
    *(half8*)(dst + 32) = o10;
    *(half8*)(dst + 40) = o11;
    *(half8*)(dst + 48) = o12;
    *(half8*)(dst + 56) = o13;
}

// half-element offset of corner voxel (zc,yc,xc) in the brick volume
__device__ __forceinline__ int brick_off(int zc, int yc, int xc)
{
    const int brick = ((zc >> 1) << 16) | ((yc >> 1) << 8) | (xc >> 1);
    const int inner = ((zc & 1) << 2) | ((yc & 1) << 1) | (xc & 1);
    return (brick << 5) | (inner << 2);
}

struct PS {
    int i[8];
    float xd, yd, zd;
    int slab;   // z0 >> 6
};

__device__ __forceinline__ PS setup_brick(float cx, float cy, float cz)
{
    const float x = fminf(fmaxf(cx, 0.0f), (float)(WW - 1));
    const float y = fminf(fmaxf(cy, 0.0f), (float)(DD - 1));
    const float z = fminf(fmaxf(cz, 0.0f), (float)(HH - 1));
    const int x0 = (int)floorf(x);
    const int y0 = (int)floorf(y);
    const int z0 = (int)floorf(z);
    const int x1 = min(x0 + 1, WW - 1);
    const int y1 = min(y0 + 1, DD - 1);
    const int z1 = min(z0 + 1, HH - 1);
    PS s;
    s.xd = x - (float)x0;
    s.yd = y - (float)y0;
    s.zd = z - (float)z0;
    s.slab = z0 >> 6;
    s.i[0] = brick_off(z0, y0, x0); s.i[1] = brick_off(z0, y0, x1);
    s.i[2] = brick_off(z0, y1, x0); s.i[3] = brick_off(z0, y1, x1);
    s.i[4] = brick_off(z1, y0, x0); s.i[5] = brick_off(z1, y0, x1);
    s.i[6] = brick_off(z1, y1, x0); s.i[7] = brick_off(z1, y1, x1);
    return s;
}

__device__ __forceinline__ void gather8(
    const _Float16* __restrict__ tv, const PS& s, half4 A[8])
{
#pragma unroll
    for (int k = 0; k < 8; ++k) A[k] = *(const half4*)(tv + (size_t)s.i[k]);
}

__device__ __forceinline__ void lerp_store(
    const half4 A[8], const PS& s, float dens[BB],
    float* __restrict__ density, int g, int p)
{
#pragma unroll
    for (int b = 0; b < BB; ++b) {
        const float c000 = (float)A[0][b], c001 = (float)A[1][b];
        const float c010 = (float)A[2][b], c011 = (float)A[3][b];
        const float c100 = (float)A[4][b], c101 = (float)A[5][b];
        const float c110 = (float)A[6][b], c111 = (float)A[7][b];
        const float c00 = c000 * (1.0f - s.xd) + c001 * s.xd;
        const float c01 = c010 * (1.0f - s.xd) + c011 * s.xd;
        const float c10 = c100 * (1.0f - s.xd) + c101 * s.xd;
        const float c11 = c110 * (1.0f - s.xd) + c111 * s.xd;
        const float c0  = c00 * (1.0f - s.yd) + c01 * s.yd;
        const float c1  = c10 * (1.0f - s.yd) + c11 * s.yd;
        dens[b] = c0 * (1.0f - s.zd) + c1 * s.zd;
        __builtin_nontemporal_store(dens[b],
            density + ((size_t)(b * GG + g)) * PP + p);
    }
}

// ---------------------------------------------------------------------------
// Fast density kernel: 2 points per thread (2 chunks per block) for 16
// outstanding gather loads. Runs twice, once per z-slab (slab = z0>>6), so
// each pass's ~132 MiB brick working set is L3-resident. All streaming
// traffic (coords, density out) is non-temporal to protect the slab in L3.
// grid = (NCHUNK/2, GG), block = 256.
// ---------------------------------------------------------------------------
__global__ __launch_bounds__(256) void k_density_h(
    const _Float16* __restrict__ tv,    // brick volume fp16
    const float* __restrict__ coords,   // [G, P, 3]
    float* __restrict__ density,        // [B*G, P]  (aliases d_out)
    float* __restrict__ chunk_sums,     // [B*G, NCHUNK]
    float* __restrict__ step_accum,     // [G]
    int slab, int do_dist)
{
    const int cpair = blockIdx.x;            // handles chunks c0, c0+1
    const int g     = blockIdx.y;
    const int t     = threadIdx.x;
    const int c0    = cpair * 2;
    const int p0    = c0 * CHUNK + t;        // p1 = p0 + 256

    __shared__ float cbuf[(2 * CHUNK + 1) * 3];
    const bool last  = (cpair == NCHUNK / 2 - 1);
    const int  nload = last ? 2 * CHUNK * 3 : (2 * CHUNK + 1) * 3;
    const float* src = coords + ((size_t)g * PP + (size_t)c0 * CHUNK) * 3;
    for (int i = t; i < nload; i += 256)
        cbuf[i] = __builtin_nontemporal_load(src + i);
    __syncthreads();

    const float ax = cbuf[3 * t + 0], ay = cbuf[3 * t + 1], az = cbuf[3 * t + 2];
    const int   u  = t + 256;
    const float bx = cbuf[3 * u + 0], by = cbuf[3 * u + 1], bz = cbuf[3 * u + 2];

    // step distances (depend only on coords; pass with do_dist=1 accumulates)
    float dist0, dist1 = 0.0f;
    {
        const float dx = cbuf[3 * (t + 1) + 0] - ax;
        const float dy = cbuf[3 * (t + 1) + 1] - ay;
        const float dz = cbuf[3 * (t + 1) + 2] - az;
        dist0 = sqrtf(dx * dx + dy * dy + dz * dz);   // p0 <= 65279 always
    }
    if (!(last && t == CHUNK - 1)) {
        const float dx = cbuf[3 * (u + 1) + 0] - bx;
        const float dy = cbuf[3 * (u + 1) + 1] - by;
        const float dz = cbuf[3 * (u + 1) + 2] - bz;
        dist1 = sqrtf(dx * dx + dy * dy + dz * dz);
    }

    const PS s0 = setup_brick(ax, ay, az);
    const PS s1 = setup_brick(bx, by, bz);
    const bool m0 = (s0.slab == slab);
    const bool m1 = (s1.slab == slab);

    // Issue both gather batches before any lerp so 16 loads overlap.
    half4 A0[8], A1[8];
    if (m0) gather8(tv, s0, A0);
    if (m1) gather8(tv, s1, A1);

    float dens0[BB] = {0, 0, 0, 0};
    float dens1[BB] = {0, 0, 0, 0};
    if (m0) lerp_store(A0, s0, dens0, density, g, p0);
    if (m1) lerp_store(A1, s1, dens1, density, g, p0 + 256);

    // Fused block reduction for both chunks + dist.
    __shared__ float wsum[4][10];
    const int lane = t & 63;
    const int wid  = t >> 6;
    float r[10] = {dens0[0], dens0[1], dens0[2], dens0[3], dist0,
                   dens1[0], dens1[1], dens1[2], dens1[3], dist1};
#pragma unroll
    for (int off = 32; off > 0; off >>= 1) {
#pragma unroll
        for (int j = 0; j < 10; ++j) r[j] += __shfl_xor(r[j], off);
    }
    if (lane == 0) {
#pragma unroll
        for (int j = 0; j < 10; ++j) wsum[wid][j] = r[j];
    }
    __syncthreads();
    if (t == 0) {
        float s[10];
#pragma unroll
        for (int j = 0; j < 10; ++j)
            s[j] = wsum[0][j] + wsum[1][j] + wsum[2][j] + wsum[3][j];
#pragma unroll
        for (int b = 0; b < BB; ++b) {
            atomicAdd(&chunk_sums[((size_t)(b * GG + g)) * NCHUNK + c0], s[b]);
            atomicAdd(&chunk_sums[((size_t)(b * GG + g)) * NCHUNK + c0 + 1], s[5 + b]);
        }
        if (do_dist) atomicAdd(&step_accum[g], s[4] + s[9]);
    }
}

// ---------------------------------------------------------------------------
// Fallback density kernel (fp32 direct gather) — used if ws too small.
// ---------------------------------------------------------------------------
__global__ __launch_bounds__(256) void k_density(
    const float* __restrict__ ct,
    const float* __restrict__ coords,
    float* __restrict__ density,
    float* __restrict__ chunk_sums,
    float* __restrict__ step_accum)
{
    const int chunk = blockIdx.x;
    const int g     = blockIdx.y;
    const int t     = threadIdx.x;
    const int p     = chunk * CHUNK + t;

    __shared__ float cbuf[(CHUNK + 1) * 3];
    const int nload = (chunk == NCHUNK - 1) ? CHUNK * 3 : (CHUNK + 1) * 3;
    const float* src = coords + ((size_t)g * PP + (size_t)chunk * CHUNK) * 3;
    for (int i = t; i < nload; i += CHUNK) cbuf[i] = src[i];
    __syncthreads();

    const float cx = cbuf[3 * t + 0];
    const float cy = cbuf[3 * t + 1];
    const float cz = cbuf[3 * t + 2];

    float dist = 0.0f;
    if (p < PP - 1) {
        const int nt = 3 * (t + 1);
        const float dx = cbuf[nt + 0] - cx;
        const float dy = cbuf[nt + 1] - cy;
        const float dz = cbuf[nt + 2] - cz;
        dist = sqrtf(dx * dx + dy * dy + dz * dz);
    }

    const float x = fminf(fmaxf(cx, 0.0f), (float)(WW - 1));
    const float y = fminf(fmaxf(cy, 0.0f), (float)(DD - 1));
    const float z = fminf(fmaxf(cz, 0.0f), (float)(HH - 1));
    const int x0 = (int)floorf(x);
    const int y0 = (int)floorf(y);
    const int z0 = (int)floorf(z);
    const int x1 = min(x0 + 1, WW - 1);
    const int y1 = min(y0 + 1, DD - 1);
    const int z1 = min(z0 + 1, HH - 1);
    const float xd = x - (float)x0, yd = y - (float)y0, zd = z - (float)z0;

    const int b00 = (z0 * DD + y0) * WW;
    const int b01 = (z0 * DD + y1) * WW;
    const int b10 = (z1 * DD + y0) * WW;
    const int b11 = (z1 * DD + y1) * WW;

    float dens[BB];
#pragma unroll
    for (int b = 0; b < BB; ++b) {
        const float* v = ct + (size_t)b * HDW;
        const float c000 = v[b00 + x0], c001 = v[b00 + x1];
        const float c010 = v[b01 + x0], c011 = v[b01 + x1];
        const float c100 = v[b10 + x0], c101 = v[b10 + x1];
        const float c110 = v[b11 + x0], c111 = v[b11 + x1];
        const float c00 = c000 * (1.0f - xd) + c001 * xd;
        const float c01 = c010 * (1.0f - xd) + c011 * xd;
        const float c10 = c100 * (1.0f - xd) + c101 * xd;
        const float c11 = c110 * (1.0f - xd) + c111 * xd;
        const float c0  = c00 * (1.0f - yd) + c01 * yd;
        const float c1  = c10 * (1.0f - yd) + c11 * yd;
        dens[b] = c0 * (1.0f - zd) + c1 * zd;
        density[((size_t)(b * GG + g)) * PP + p] = dens[b];
    }

    __shared__ float wsum[4][5];
    const int lane = t & 63;
    const int wid  = t >> 6;
    float r0 = dens[0], r1 = dens[1], r2 = dens[2], r3 = dens[3], rd = dist;
#pragma unroll
    for (int off = 32; off > 0; off >>= 1) {
        r0 += __shfl_xor(r0, off);
        r1 += __shfl_xor(r1, off);
        r2 += __shfl_xor(r2, off);
        r3 += __shfl_xor(r3, off);
        rd += __shfl_xor(rd, off);
    }
    if (lane == 0) {
        wsum[wid][0] = r0; wsum[wid][1] = r1; wsum[wid][2] = r2;
        wsum[wid][3] = r3; wsum[wid][4] = rd;
    }
    __syncthreads();
    if (t == 0) {
        float s0 = 0, s1 = 0, s2 = 0, s3 = 0, sd = 0;
#pragma unroll
        for (int w = 0; w < 4; ++w) {
            s0 += wsum[w][0]; s1 += wsum[w][1]; s2 += wsum[w][2];
            s3 += wsum[w][3]; sd += wsum[w][4];
        }
        atomicAdd(&chunk_sums[((size_t)(0 * GG + g)) * NCHUNK + chunk], s0);
        atomicAdd(&chunk_sums[((size_t)(1 * GG + g)) * NCHUNK + chunk], s1);
        atomicAdd(&chunk_sums[((size_t)(2 * GG + g)) * NCHUNK + chunk], s2);
        atomicAdd(&chunk_sums[((size_t)(3 * GG + g)) * NCHUNK + chunk], s3);
        atomicAdd(&step_accum[g], sd);
    }
}

// ---------------------------------------------------------------------------
// Kernel 2: in-place exclusive scan of chunk sums per row. grid = B*G, blk=256
// ---------------------------------------------------------------------------
__global__ __launch_bounds__(256) void k_scan_chunks(float* __restrict__ cs)
{
    const int row = blockIdx.x;      // b*G + g
    const int t   = threadIdx.x;
    const int lane = t & 63;
    const int wid  = t >> 6;

    float v = cs[(size_t)row * NCHUNK + t];
    const float own = v;
#pragma unroll
    for (int d = 1; d < 64; d <<= 1) {
        const float n = __shfl_up(v, d);
        if (lane >= d) v += n;
    }
    __shared__ float ws[4];
    if (lane == 63) ws[wid] = v;
    __syncthreads();
    float prefix = 0.0f;
    for (int w = 0; w < wid; ++w) prefix += ws[w];
    cs[(size_t)row * NCHUNK + t] = prefix + v - own;   // exclusive
}

// ---------------------------------------------------------------------------
// Kernel 3: final scan + scale, in place over d_out. grid = (NCHUNK, GG)
// ---------------------------------------------------------------------------
__global__ __launch_bounds__(256) void k_output(
    float* __restrict__ out,
    const float* __restrict__ cs,
    const float* __restrict__ step_accum)
{
    const int chunk = blockIdx.x;
    const int g     = blockIdx.y;
    const int t     = threadIdx.x;
    const int p     = chunk * CHUNK + t;
    const int lane  = t & 63;
    const int wid   = t >> 6;

    const float step = step_accum[g] * (2.0f / (float)(PP - 1));

    float d[BB], v[BB];
#pragma unroll
    for (int b = 0; b < BB; ++b) {
        d[b] = __builtin_nontemporal_load(out + ((size_t)(b * GG + g)) * PP + p);
        v[b] = d[b];
    }

#pragma unroll
    for (int dd = 1; dd < 64; dd <<= 1) {
#pragma unroll
        for (int b = 0; b < BB; ++b) {
            const float n = __shfl_up(v[b], dd);
            if (lane >= dd) v[b] += n;
        }
    }
    __shared__ float ws[4][BB];
    if (lane == 63) {
#pragma unroll
        for (int b = 0; b < BB; ++b) ws[wid][b] = v[b];
    }
    __syncthreads();

#pragma unroll
    for (int b = 0; b < BB; ++b) {
        float prefix = 0.0f;
        for (int w = 0; w < wid; ++w) prefix += ws[w][b];
        const float excl = cs[((size_t)(b * GG + g)) * NCHUNK + chunk];
        const float incl = excl + prefix + v[b];
        __builtin_nontemporal_store(step * (incl + 0.5f * d[b]),
            out + ((size_t)(b * GG + g)) * PP + p);
    }
}

// ---------------------------------------------------------------------------
extern "C" void kernel_launch(void* const* d_in, const int* in_sizes, int n_in,
                              void* d_out, int out_size, void* d_ws, size_t ws_size,
                              hipStream_t stream)
{
    const float* ct     = (const float*)d_in[0];
    const float* coords = (const float*)d_in[1];
    float* out = (float*)d_out;

    const size_t volBytes = (size_t)HDW * BB * sizeof(_Float16);        // 256 MiB
    const size_t csCount  = (size_t)BB * GG * NCHUNK;
    const size_t needed   = volBytes + (csCount + GG) * sizeof(float);

    if (ws_size >= needed) {
        _Float16* tv       = (_Float16*)d_ws;
        float* chunk_sums  = (float*)((char*)d_ws + volBytes);
        float* step_accum  = chunk_sums + csCount;

        (void)hipMemsetAsync(chunk_sums, 0, (csCount + GG) * sizeof(float), stream);
        k_transpose<<<NBRICK / 2 / 256, 256, 0, stream>>>(ct, tv);
        // slab 1 first: transpose wrote the volume in ascending z, so the
        // high-z half is the part most likely still resident in L3.
        k_density_h<<<dim3(NCHUNK / 2, GG), 256, 0, stream>>>(tv, coords, out, chunk_sums, step_accum, 1, 1);
        k_density_h<<<dim3(NCHUNK / 2, GG), 256, 0, stream>>>(tv, coords, out, chunk_sums, step_accum, 0, 0);
        k_scan_chunks<<<BB * GG, 256, 0, stream>>>(chunk_sums);
        k_output<<<dim3(NCHUNK, GG), 256, 0, stream>>>(out, chunk_sums, step_accum);
    } else {
        float* chunk_sums  = (float*)d_ws;
        float* step_accum  = chunk_sums + csCount;

        (void)hipMemsetAsync(chunk_sums, 0, (csCount + GG) * sizeof(float), stream);
        k_density<<<dim3(NCHUNK, GG), 256, 0, stream>>>(ct, coords, out, chunk_sums, step_accum);
        k_scan_chunks<<<BB * GG, 256, 0, stream>>>(chunk_sums);
        k_output<<<dim3(NCHUNK, GG), 256, 0, stream>>>(out, chunk_sums, step_accum);
    }
}

// Round 4
// 1006.049 us; speedup vs baseline: 1.1685x; 1.0406x over previous
//
#include <hip/hip_runtime.h>
#include <math.h>

// Problem constants (fixed by setup_inputs)
#define BB 4
#define HH 128
#define DD 512
#define WW 512
#define GG 72
#define PP 65536
#define CHUNK 256
#define NCHUNK (PP / CHUNK)          // 256
#define HDW (HH * DD * WW)           // 33,554,432
#define NBRICK (HDW / 8)             // 4,194,304 bricks of 2x2x2 voxels

typedef _Float16 half4 __attribute__((ext_vector_type(4)));
typedef _Float16 half8 __attribute__((ext_vector_type(8)));
typedef float f4 __attribute__((ext_vector_type(4)));   // NT-load-compatible

// ---------------------------------------------------------------------------
// Transpose + quantize into 64B bricks:
//   ct [B,H,D,W] fp32  ->  tv bricks: brick(bz,by,bx) holds 2x2x2 voxels x 4
//   batches fp16, inner layout [oz][oy][ox][b] -> 32 halves = 64 B = 1 line.
// One thread per brick-PAIR (adjacent in x): f4 NT reads, 128 B write.
// NT on ct reads so the 512 MiB stream doesn't evict the tv writes from L3 —
// the density pass depends on tv being L3-resident.
// ---------------------------------------------------------------------------
__global__ __launch_bounds__(256) void k_transpose(
    const float* __restrict__ ct, _Float16* __restrict__ tv)
{
    const int n2  = blockIdx.x * 256 + threadIdx.x;  // brick-pair index
    const int bxp = n2 & 127;                        // 128 pairs per x-row
    const int by  = (n2 >> 7) & 255;                 // DD/2
    const int bz  = n2 >> 15;                        // HH/2
    const size_t base = ((size_t)(2 * bz) * DD + 2 * by) * WW + 4 * bxp;

    half8 o00, o01, o02, o03;   // brick 0: inner pairs (oz,oy) = 00,01,10,11
    half8 o10, o11, o12, o13;   // brick 1
#pragma unroll
    for (int b = 0; b < BB; ++b) {
        const float* v = ct + (size_t)b * HDW + base;
        const f4 f00 = __builtin_nontemporal_load((const f4*)(v));
        const f4 f01 = __builtin_nontemporal_load((const f4*)(v + WW));
        const f4 f10 = __builtin_nontemporal_load((const f4*)(v + (size_t)DD * WW));
        const f4 f11 = __builtin_nontemporal_load((const f4*)(v + (size_t)DD * WW + WW));
        o00[b] = (_Float16)f00[0]; o00[4 + b] = (_Float16)f00[1];
        o01[b] = (_Float16)f01[0]; o01[4 + b] = (_Float16)f01[1];
        o02[b] = (_Float16)f10[0]; o02[4 + b] = (_Float16)f10[1];
        o03[b] = (_Float16)f11[0]; o03[4 + b] = (_Float16)f11[1];
        o10[b] = (_Float16)f00[2]; o10[4 + b] = (_Float16)f00[3];
        o11[b] = (_Float16)f01[2]; o11[4 + b] = (_Float16)f01[3];
        o12[b] = (_Float16)f10[2]; o12[4 + b] = (_Float16)f10[3];
        o13[b] = (_Float16)f11[2]; o13[4 + b] = (_Float16)f11[3];
    }
    _Float16* dst = tv + (size_t)n2 * 64;   // two consecutive 64 B bricks
    *(half8*)(dst)      = o00;
    *(half8*)(dst + 8)  = o01;
    *(half8*)(dst + 16) = o02;
    *(half8*)(dst + 24) = o03;
    *(half8*)(dst + 32) = o10;
    *(half8*)(dst + 40) = o11;
    *(half8*)(dst + 48) = o12;
    *(half8*)(dst + 56) = o13;
}

// half-element offset of corner voxel (zc,yc,xc) in the brick volume
__device__ __forceinline__ int brick_off(int zc, int yc, int xc)
{
    const int brick = ((zc >> 1) << 16) | ((yc >> 1) << 8) | (xc >> 1);
    const int inner = ((zc & 1) << 2) | ((yc & 1) << 1) | (xc & 1);
    return (brick << 5) | (inner << 2);
}

struct PS {
    int i[8];
    float xd, yd, zd;
};

__device__ __forceinline__ PS setup_brick(float cx, float cy, float cz)
{
    const float x = fminf(fmaxf(cx, 0.0f), (float)(WW - 1));
    const float y = fminf(fmaxf(cy, 0.0f), (float)(DD - 1));
    const float z = fminf(fmaxf(cz, 0.0f), (float)(HH - 1));
    const int x0 = (int)floorf(x);
    const int y0 = (int)floorf(y);
    const int z0 = (int)floorf(z);
    const int x1 = min(x0 + 1, WW - 1);
    const int y1 = min(y0 + 1, DD - 1);
    const int z1 = min(z0 + 1, HH - 1);
    PS s;
    s.xd = x - (float)x0;
    s.yd = y - (float)y0;
    s.zd = z - (float)z0;
    s.i[0] = brick_off(z0, y0, x0); s.i[1] = brick_off(z0, y0, x1);
    s.i[2] = brick_off(z0, y1, x0); s.i[3] = brick_off(z0, y1, x1);
    s.i[4] = brick_off(z1, y0, x0); s.i[5] = brick_off(z1, y0, x1);
    s.i[6] = brick_off(z1, y1, x0); s.i[7] = brick_off(z1, y1, x1);
    return s;
}

__device__ __forceinline__ void gather8(
    const _Float16* __restrict__ tv, const PS& s, half4 A[8])
{
#pragma unroll
    for (int k = 0; k < 8; ++k) A[k] = *(const half4*)(tv + (size_t)s.i[k]);
}

__device__ __forceinline__ void lerp_store(
    const half4 A[8], const PS& s, float dens[BB],
    float* __restrict__ density, int g, int p)
{
#pragma unroll
    for (int b = 0; b < BB; ++b) {
        const float c000 = (float)A[0][b], c001 = (float)A[1][b];
        const float c010 = (float)A[2][b], c011 = (float)A[3][b];
        const float c100 = (float)A[4][b], c101 = (float)A[5][b];
        const float c110 = (float)A[6][b], c111 = (float)A[7][b];
        const float c00 = c000 * (1.0f - s.xd) + c001 * s.xd;
        const float c01 = c010 * (1.0f - s.xd) + c011 * s.xd;
        const float c10 = c100 * (1.0f - s.xd) + c101 * s.xd;
        const float c11 = c110 * (1.0f - s.xd) + c111 * s.xd;
        const float c0  = c00 * (1.0f - s.yd) + c01 * s.yd;
        const float c1  = c10 * (1.0f - s.yd) + c11 * s.yd;
        dens[b] = c0 * (1.0f - s.zd) + c1 * s.zd;
        __builtin_nontemporal_store(dens[b],
            density + ((size_t)(b * GG + g)) * PP + p);
    }
}

// ---------------------------------------------------------------------------
// Density kernel, SINGLE pass: 2 points per thread (2 chunks per block) for
// 16 unmasked outstanding gather loads. Relies on tv (256 MiB) being
// L3-resident after the transpose; all streaming traffic (coords, density
// out) is non-temporal so it stays resident. Each block owns chunks c0,c0+1
// exclusively -> chunk_sums written with plain stores (no atomics/memset).
// grid = (NCHUNK/2, GG), block = 256.
// ---------------------------------------------------------------------------
__global__ __launch_bounds__(256) void k_density_h(
    const _Float16* __restrict__ tv,    // brick volume fp16
    const float* __restrict__ coords,   // [G, P, 3]
    float* __restrict__ density,        // [B*G, P]  (aliases d_out)
    float* __restrict__ chunk_sums,     // [B*G, NCHUNK]
    float* __restrict__ step_accum)     // [G]
{
    const int cpair = blockIdx.x;            // handles chunks c0, c0+1
    const int g     = blockIdx.y;
    const int t     = threadIdx.x;
    const int c0    = cpair * 2;
    const int p0    = c0 * CHUNK + t;        // p1 = p0 + 256

    __shared__ float cbuf[(2 * CHUNK + 1) * 3];
    const bool last  = (cpair == NCHUNK / 2 - 1);
    const int  nload = last ? 2 * CHUNK * 3 : (2 * CHUNK + 1) * 3;
    const float* src = coords + ((size_t)g * PP + (size_t)c0 * CHUNK) * 3;
    for (int i = t; i < nload; i += 256)
        cbuf[i] = __builtin_nontemporal_load(src + i);
    __syncthreads();

    const float ax = cbuf[3 * t + 0], ay = cbuf[3 * t + 1], az = cbuf[3 * t + 2];
    const int   u  = t + 256;
    const float bx = cbuf[3 * u + 0], by = cbuf[3 * u + 1], bz = cbuf[3 * u + 2];

    float dist0, dist1 = 0.0f;
    {
        const float dx = cbuf[3 * (t + 1) + 0] - ax;
        const float dy = cbuf[3 * (t + 1) + 1] - ay;
        const float dz = cbuf[3 * (t + 1) + 2] - az;
        dist0 = sqrtf(dx * dx + dy * dy + dz * dz);   // p0 <= 65279 always
    }
    if (!(last && t == CHUNK - 1)) {
        const float dx = cbuf[3 * (u + 1) + 0] - bx;
        const float dy = cbuf[3 * (u + 1) + 1] - by;
        const float dz = cbuf[3 * (u + 1) + 2] - bz;
        dist1 = sqrtf(dx * dx + dy * dy + dz * dz);
    }

    const PS s0 = setup_brick(ax, ay, az);
    const PS s1 = setup_brick(bx, by, bz);

    // Issue both gather batches before any lerp so 16 loads overlap.
    half4 A0[8], A1[8];
    gather8(tv, s0, A0);
    gather8(tv, s1, A1);

    float dens0[BB], dens1[BB];
    lerp_store(A0, s0, dens0, density, g, p0);
    lerp_store(A1, s1, dens1, density, g, p0 + 256);

    // Fused block reduction for both chunks + dist.
    __shared__ float wsum[4][10];
    const int lane = t & 63;
    const int wid  = t >> 6;
    float r[10] = {dens0[0], dens0[1], dens0[2], dens0[3], dist0,
                   dens1[0], dens1[1], dens1[2], dens1[3], dist1};
#pragma unroll
    for (int off = 32; off > 0; off >>= 1) {
#pragma unroll
        for (int j = 0; j < 10; ++j) r[j] += __shfl_xor(r[j], off);
    }
    if (lane == 0) {
#pragma unroll
        for (int j = 0; j < 10; ++j) wsum[wid][j] = r[j];
    }
    __syncthreads();
    if (t == 0) {
        float s[10];
#pragma unroll
        for (int j = 0; j < 10; ++j)
            s[j] = wsum[0][j] + wsum[1][j] + wsum[2][j] + wsum[3][j];
#pragma unroll
        for (int b = 0; b < BB; ++b) {
            chunk_sums[((size_t)(b * GG + g)) * NCHUNK + c0]     = s[b];
            chunk_sums[((size_t)(b * GG + g)) * NCHUNK + c0 + 1] = s[5 + b];
        }
        atomicAdd(&step_accum[g], s[4] + s[9]);
    }
}

// ---------------------------------------------------------------------------
// Fallback density kernel (fp32 direct gather) — used if ws too small.
// ---------------------------------------------------------------------------
__global__ __launch_bounds__(256) void k_density(
    const float* __restrict__ ct,
    const float* __restrict__ coords,
    float* __restrict__ density,
    float* __restrict__ chunk_sums,
    float* __restrict__ step_accum)
{
    const int chunk = blockIdx.x;
    const int g     = blockIdx.y;
    const int t     = threadIdx.x;
    const int p     = chunk * CHUNK + t;

    __shared__ float cbuf[(CHUNK + 1) * 3];
    const int nload = (chunk == NCHUNK - 1) ? CHUNK * 3 : (CHUNK + 1) * 3;
    const float* src = coords + ((size_t)g * PP + (size_t)chunk * CHUNK) * 3;
    for (int i = t; i < nload; i += CHUNK) cbuf[i] = src[i];
    __syncthreads();

    const float cx = cbuf[3 * t + 0];
    const float cy = cbuf[3 * t + 1];
    const float cz = cbuf[3 * t + 2];

    float dist = 0.0f;
    if (p < PP - 1) {
        const int nt = 3 * (t + 1);
        const float dx = cbuf[nt + 0] - cx;
        const float dy = cbuf[nt + 1] - cy;
        const float dz = cbuf[nt + 2] - cz;
        dist = sqrtf(dx * dx + dy * dy + dz * dz);
    }

    const float x = fminf(fmaxf(cx, 0.0f), (float)(WW - 1));
    const float y = fminf(fmaxf(cy, 0.0f), (float)(DD - 1));
    const float z = fminf(fmaxf(cz, 0.0f), (float)(HH - 1));
    const int x0 = (int)floorf(x);
    const int y0 = (int)floorf(y);
    const int z0 = (int)floorf(z);
    const int x1 = min(x0 + 1, WW - 1);
    const int y1 = min(y0 + 1, DD - 1);
    const int z1 = min(z0 + 1, HH - 1);
    const float xd = x - (float)x0, yd = y - (float)y0, zd = z - (float)z0;

    const int b00 = (z0 * DD + y0) * WW;
    const int b01 = (z0 * DD + y1) * WW;
    const int b10 = (z1 * DD + y0) * WW;
    const int b11 = (z1 * DD + y1) * WW;

    float dens[BB];
#pragma unroll
    for (int b = 0; b < BB; ++b) {
        const float* v = ct + (size_t)b * HDW;
        const float c000 = v[b00 + x0], c001 = v[b00 + x1];
        const float c010 = v[b01 + x0], c011 = v[b01 + x1];
        const float c100 = v[b10 + x0], c101 = v[b10 + x1];
        const float c110 = v[b11 + x0], c111 = v[b11 + x1];
        const float c00 = c000 * (1.0f - xd) + c001 * xd;
        const float c01 = c010 * (1.0f - xd) + c011 * xd;
        const float c10 = c100 * (1.0f - xd) + c101 * xd;
        const float c11 = c110 * (1.0f - xd) + c111 * xd;
        const float c0  = c00 * (1.0f - yd) + c01 * yd;
        const float c1  = c10 * (1.0f - yd) + c11 * yd;
        dens[b] = c0 * (1.0f - zd) + c1 * zd;
        density[((size_t)(b * GG + g)) * PP + p] = dens[b];
    }

    __shared__ float wsum[4][5];
    const int lane = t & 63;
    const int wid  = t >> 6;
    float r0 = dens[0], r1 = dens[1], r2 = dens[2], r3 = dens[3], rd = dist;
#pragma unroll
    for (int off = 32; off > 0; off >>= 1) {
        r0 += __shfl_xor(r0, off);
        r1 += __shfl_xor(r1, off);
        r2 += __shfl_xor(r2, off);
        r3 += __shfl_xor(r3, off);
        rd += __shfl_xor(rd, off);
    }
    if (lane == 0) {
        wsum[wid][0] = r0; wsum[wid][1] = r1; wsum[wid][2] = r2;
        wsum[wid][3] = r3; wsum[wid][4] = rd;
    }
    __syncthreads();
    if (t == 0) {
        float s0 = 0, s1 = 0, s2 = 0, s3 = 0, sd = 0;
#pragma unroll
        for (int w = 0; w < 4; ++w) {
            s0 += wsum[w][0]; s1 += wsum[w][1]; s2 += wsum[w][2];
            s3 += wsum[w][3]; sd += wsum[w][4];
        }
        chunk_sums[((size_t)(0 * GG + g)) * NCHUNK + chunk] = s0;
        chunk_sums[((size_t)(1 * GG + g)) * NCHUNK + chunk] = s1;
        chunk_sums[((size_t)(2 * GG + g)) * NCHUNK + chunk] = s2;
        chunk_sums[((size_t)(3 * GG + g)) * NCHUNK + chunk] = s3;
        atomicAdd(&step_accum[g], sd);
    }
}

// ---------------------------------------------------------------------------
// Kernel 2: in-place exclusive scan of chunk sums per row. grid = B*G, blk=256
// ---------------------------------------------------------------------------
__global__ __launch_bounds__(256) void k_scan_chunks(float* __restrict__ cs)
{
    const int row = blockIdx.x;      // b*G + g
    const int t   = threadIdx.x;
    const int lane = t & 63;
    const int wid  = t >> 6;

    float v = cs[(size_t)row * NCHUNK + t];
    const float own = v;
#pragma unroll
    for (int d = 1; d < 64; d <<= 1) {
        const float n = __shfl_up(v, d);
        if (lane >= d) v += n;
    }
    __shared__ float ws[4];
    if (lane == 63) ws[wid] = v;
    __syncthreads();
    float prefix = 0.0f;
    for (int w = 0; w < wid; ++w) prefix += ws[w];
    cs[(size_t)row * NCHUNK + t] = prefix + v - own;   // exclusive
}

// ---------------------------------------------------------------------------
// Kernel 3: final scan + scale, in place over d_out. grid = (NCHUNK, GG)
// ---------------------------------------------------------------------------
__global__ __launch_bounds__(256) void k_output(
    float* __restrict__ out,
    const float* __restrict__ cs,
    const float* __restrict__ step_accum)
{
    const int chunk = blockIdx.x;
    const int g     = blockIdx.y;
    const int t     = threadIdx.x;
    const int p     = chunk * CHUNK + t;
    const int lane  = t & 63;
    const int wid   = t >> 6;

    const float step = step_accum[g] * (2.0f / (float)(PP - 1));

    float d[BB], v[BB];
#pragma unroll
    for (int b = 0; b < BB; ++b) {
        d[b] = __builtin_nontemporal_load(out + ((size_t)(b * GG + g)) * PP + p);
        v[b] = d[b];
    }

#pragma unroll
    for (int dd = 1; dd < 64; dd <<= 1) {
#pragma unroll
        for (int b = 0; b < BB; ++b) {
            const float n = __shfl_up(v[b], dd);
            if (lane >= dd) v[b] += n;
        }
    }
    __shared__ float ws[4][BB];
    if (lane == 63) {
#pragma unroll
        for (int b = 0; b < BB; ++b) ws[wid][b] = v[b];
    }
    __syncthreads();

#pragma unroll
    for (int b = 0; b < BB; ++b) {
        float prefix = 0.0f;
        for (int w = 0; w < wid; ++w) prefix += ws[w][b];
        const float excl = cs[((size_t)(b * GG + g)) * NCHUNK + chunk];
        const float incl = excl + prefix + v[b];
        __builtin_nontemporal_store(step * (incl + 0.5f * d[b]),
            out + ((size_t)(b * GG + g)) * PP + p);
    }
}

// ---------------------------------------------------------------------------
extern "C" void kernel_launch(void* const* d_in, const int* in_sizes, int n_in,
                              void* d_out, int out_size, void* d_ws, size_t ws_size,
                              hipStream_t stream)
{
    const float* ct     = (const float*)d_in[0];
    const float* coords = (const float*)d_in[1];
    float* out = (float*)d_out;

    const size_t volBytes = (size_t)HDW * BB * sizeof(_Float16);        // 256 MiB
    const size_t csCount  = (size_t)BB * GG * NCHUNK;
    const size_t needed   = volBytes + (csCount + GG) * sizeof(float);

    if (ws_size >= needed) {
        _Float16* tv       = (_Float16*)d_ws;
        float* chunk_sums  = (float*)((char*)d_ws + volBytes);
        float* step_accum  = chunk_sums + csCount;

        // only step_accum needs zeroing (chunk_sums is plain-stored)
        (void)hipMemsetAsync(step_accum, 0, GG * sizeof(float), stream);
        k_transpose<<<NBRICK / 2 / 256, 256, 0, stream>>>(ct, tv);
        k_density_h<<<dim3(NCHUNK / 2, GG), 256, 0, stream>>>(tv, coords, out, chunk_sums, step_accum);
        k_scan_chunks<<<BB * GG, 256, 0, stream>>>(chunk_sums);
        k_output<<<dim3(NCHUNK, GG), 256, 0, stream>>>(out, chunk_sums, step_accum);
    } else {
        float* chunk_sums  = (float*)d_ws;
        float* step_accum  = chunk_sums + csCount;

        (void)hipMemsetAsync(step_accum, 0, GG * sizeof(float), stream);
        k_density<<<dim3(NCHUNK, GG), 256, 0, stream>>>(ct, coords, out, chunk_sums, step_accum);
        k_scan_chunks<<<BB * GG, 256, 0, stream>>>(chunk_sums);
        k_output<<<dim3(NCHUNK, GG), 256, 0, stream>>>(out, chunk_sums, step_accum);
    }
}